// Round 18
// baseline (32.571 us; speedup 1.0000x reference)
//
#include <hip/hip_runtime.h>
#include <math.h>

#define B_  16
#define T_  16
#define N_  256
#define D_  384
#define Q_  384
#define K_  16
#define BT_ (B_ * T_)

typedef float f32x4 __attribute__((ext_vector_type(4)));

// R18 = R17 (31.92us) + barrier removal in the softmax-stats phase:
// every wave redundantly reduces all 256 e/cnt values (4/lane + shfl_xor,
// bitwise-identical across waves -> deterministic), computes inv locally,
// and the scatter happens with no intervening __syncthreads. 9 -> 8 barriers.
__global__ __launch_bounds__(1024, 4)
void fused_kernel(const float* __restrict__ queries,  // [BT_, Q_]
                  const float* __restrict__ patch,    // [BT_, N_, D_]
                  const float* __restrict__ W_in,     // [Q_, D_]
                  const float* __restrict__ b_in,     // [D_]
                  const float* __restrict__ W_out,    // [D_, Q_]
                  const float* __restrict__ b_out,    // [Q_]
                  float* __restrict__ out)            // [BT_, Q_]
{
    const int bt   = blockIdx.x;
    const int tid  = threadIdx.x;       // 0..1023
    const int lane = tid & 63;
    const int wave = tid >> 6;          // 0..15

    __shared__ __align__(16) float s_q[Q_];
    __shared__ __align__(16) float s_qp[D_];
    __shared__ __align__(16) float s_sc[N_];
    __shared__ __align__(16) unsigned s_ku[N_];   // rank keys
    __shared__ __align__(16) int   s_cnt4[N_][4];
    __shared__ float s_red[4];
    __shared__ float s_w[K_];
    __shared__ int   s_ix[K_];
    __shared__ __align__(16) float s_p8[8][D_];   // split-K partials (reused)
    __shared__ __align__(16) float s_od[D_];

    const float* __restrict__ ptile = patch + (size_t)bt * N_ * D_;

    // ---- stage query row ----
    if (tid < Q_) s_q[tid] = queries[(size_t)bt * Q_ + tid];
    __syncthreads();

    const int g16 = lane >> 4;          // 0..3
    const int sl  = lane & 15;
    const int n0  = wave * 4 + g16;     // rows n0 + {0,64,128,192}

    f32x4 A[6], Bu[6], C[6];

#define LOADROW(dst, it) {                                                     \
        const float* pr = ptile + (size_t)(n0 + (it) * 64) * D_;               \
        _Pragma("unroll")                                                      \
        for (int c = 0; c < 6; ++c)                                            \
            dst[c] = __builtin_nontemporal_load(                               \
                reinterpret_cast<const f32x4*>(pr + c * 64 + 4 * sl)); }

#define DOTSTORE(src, it) {                                                    \
        float p = 0.f;                                                         \
        _Pragma("unroll")                                                      \
        for (int c = 0; c < 6; ++c)                                            \
            p += src[c].x * qv[c].x + src[c].y * qv[c].y                       \
               + src[c].z * qv[c].z + src[c].w * qv[c].w;                      \
        _Pragma("unroll")                                                      \
        for (int off = 8; off; off >>= 1) p += __shfl_xor(p, off, 16);         \
        if (sl == 0) {                                                         \
            const int nn = n0 + (it) * 64;                                     \
            s_sc[nn] = p;                                                      \
            const unsigned u = __float_as_uint(p);                             \
            const unsigned ord = u ^ ((unsigned)((int)u >> 31) | 0x80000000u); \
            s_ku[nn] = (ord & 0xFFFFFF00u) | (255u - (unsigned)nn);            \
        } }

    // ---- issue patch prefetch rows 0,1,2 (independent of q_proj) ----
    LOADROW(A, 0)
    LOADROW(Bu, 1)
    LOADROW(C, 2)
    __builtin_amdgcn_sched_barrier(0);  // pin prefetch issue before qproj

    // ---- q_proj while prefetch streams: 768 thr, 8-way split-K, float4 W ----
    if (tid < 768) {
        const int s = tid / 96;         // k-split 0..7 -> q in [s*48, s*48+48)
        const int g = tid % 96;         // output cols 4g..4g+3
        float4 acc = {0.f, 0.f, 0.f, 0.f};
        const float* wp = W_in + (size_t)(s * 48) * D_ + 4 * g;
        #pragma unroll 4
        for (int qq = 0; qq < 48; ++qq) {
            const float4 w = *reinterpret_cast<const float4*>(wp + (size_t)qq * D_);
            const float qs = s_q[s * 48 + qq];
            acc.x += qs * w.x; acc.y += qs * w.y;
            acc.z += qs * w.z; acc.w += qs * w.w;
        }
        *reinterpret_cast<float4*>(&s_p8[s][4 * g]) = acc;
    }
    __syncthreads();
    if (tid < D_) {
        float v = b_in[tid];
        #pragma unroll
        for (int s = 0; s < 8; ++s) v += s_p8[s][tid];
        s_qp[tid] = v;
    }
    __syncthreads();   // prefetch has arrived under qproj

    // ---- scores: rows 0,1,2 from prefetch; row 3 pipelined ----
    {
        const f32x4* s_qp4 = reinterpret_cast<const f32x4*>(s_qp);
        f32x4 qv[6];
        #pragma unroll
        for (int c = 0; c < 6; ++c) qv[c] = s_qp4[c * 16 + sl];

        DOTSTORE(A, 0)
        LOADROW(A, 3)
        DOTSTORE(Bu, 1)
        DOTSTORE(C, 2)
        DOTSTORE(A, 3)
    }
#undef LOADROW
#undef DOTSTORE
    __syncthreads();

    // ---- block max (waves 0-3) + key rank counts (all 1024 thr, rotated) ----
    if (tid < N_) {
        float v = s_sc[tid];
        #pragma unroll
        for (int off = 32; off; off >>= 1) v = fmaxf(v, __shfl_xor(v, off));
        if (lane == 0) s_red[wave] = v;
    }
    {
        const int i   = tid >> 2;       // 0..255
        const int sub = tid & 3;        // chunk [sub*64, sub*64+64)
        const unsigned ki = s_ku[i];
        const uint4* k4 = reinterpret_cast<const uint4*>(s_ku);
        int c = 0;
        #pragma unroll
        for (int jj = 0; jj < 16; ++jj) {
            const int jr = (jj + sub * 4) & 15;          // rotate start
            const uint4 v = k4[sub * 16 + jr];
            c += (int)(v.x > ki) + (int)(v.y > ki)
               + (int)(v.z > ki) + (int)(v.w > ki);
        }
        s_cnt4[i][sub] = c;
    }
    __syncthreads();

    // ---- Z, SK: every wave reduces all 256 redundantly (NO barrier), then
    //      scatter weight_i = e_i / (SK + EPS*Z) immediately ----
    {
        const float mx = fmaxf(fmaxf(s_red[0], s_red[1]), fmaxf(s_red[2], s_red[3]));
        float z = 0.f, sk = 0.f;
        #pragma unroll
        for (int v = 0; v < 4; ++v) {
            const int i = lane + 64 * v;
            const int4 c4 = reinterpret_cast<const int4*>(s_cnt4)[i];
            const int ci = c4.x + c4.y + c4.z + c4.w;
            const float ei = __expf(s_sc[i] - mx);
            z += ei;
            sk += (ci < K_) ? ei : 0.f;
        }
        #pragma unroll
        for (int off = 32; off; off >>= 1) {
            z  += __shfl_xor(z, off);
            sk += __shfl_xor(sk, off);
        }
        const float inv = 1.f / (sk + 1e-8f * z);   // identical in every wave
        if (tid < N_) {
            const int4 c4 = reinterpret_cast<const int4*>(s_cnt4)[tid];
            const int cnt = c4.x + c4.y + c4.z + c4.w;
            if (cnt < K_) {
                s_ix[cnt] = tid;
                s_w[cnt]  = __expf(s_sc[tid] - mx) * inv;
            }
        }
    }
    __syncthreads();

    // ---- W_out prefetch (independent of s_od) + weighted sum over K rows ----
    float4 wpre[8];
    const float* wp = W_out;
    if (tid < 768) {
        const int s = tid / 96;
        const int g = tid % 96;
        wp = W_out + (size_t)(s * 48) * Q_ + 4 * g;
        #pragma unroll
        for (int p = 0; p < 8; ++p)
            wpre[p] = *reinterpret_cast<const float4*>(wp + (size_t)p * Q_);
    }
    __builtin_amdgcn_sched_barrier(0);  // issue W_out loads before wsum

    if (tid < D_) {
        float a0 = 0.f, a1 = 0.f, a2 = 0.f, a3 = 0.f;
        #pragma unroll
        for (int j = 0; j < K_; j += 4) {
            a0 += s_w[j + 0] * ptile[(size_t)s_ix[j + 0] * D_ + tid];
            a1 += s_w[j + 1] * ptile[(size_t)s_ix[j + 1] * D_ + tid];
            a2 += s_w[j + 2] * ptile[(size_t)s_ix[j + 2] * D_ + tid];
            a3 += s_w[j + 3] * ptile[(size_t)s_ix[j + 3] * D_ + tid];
        }
        s_od[tid] = (a0 + a1) + (a2 + a3);
    }
    __syncthreads();

    // ---- out-proj: 768 thr, 8-way split-K; 8 prefetched + 40 streamed ----
    if (tid < 768) {
        const int s = tid / 96;
        const int g = tid % 96;
        const int base = s * 48;
        float4 acc = {0.f, 0.f, 0.f, 0.f};
        #pragma unroll
        for (int p = 0; p < 8; ++p) {
            const float ov = s_od[base + p];
            acc.x += ov * wpre[p].x; acc.y += ov * wpre[p].y;
            acc.z += ov * wpre[p].z; acc.w += ov * wpre[p].w;
        }
        #pragma unroll 4
        for (int dd = 8; dd < 48; ++dd) {
            const float4 w = *reinterpret_cast<const float4*>(wp + (size_t)dd * Q_);
            const float ov = s_od[base + dd];
            acc.x += ov * w.x; acc.y += ov * w.y;
            acc.z += ov * w.z; acc.w += ov * w.w;
        }
        *reinterpret_cast<float4*>(&s_p8[s][4 * g]) = acc;
    }
    __syncthreads();
    if (tid < Q_) {
        float v = b_out[tid];
        #pragma unroll
        for (int s = 0; s < 8; ++s) v += s_p8[s][tid];
        out[(size_t)bt * Q_ + tid] = v;
    }
}

extern "C" void kernel_launch(void* const* d_in, const int* in_sizes, int n_in,
                              void* d_out, int out_size, void* d_ws, size_t ws_size,
                              hipStream_t stream) {
    const float* queries = (const float*)d_in[0];
    const float* patch   = (const float*)d_in[1];
    const float* W_in    = (const float*)d_in[2];
    const float* b_in    = (const float*)d_in[3];
    const float* W_out   = (const float*)d_in[4];
    const float* b_out   = (const float*)d_in[5];
    float* out = (float*)d_out;

    fused_kernel<<<dim3(BT_), dim3(1024), 0, stream>>>(
        queries, patch, W_in, b_in, W_out, b_out, out);
}

// Round 19
// 32.360 us; speedup vs baseline: 1.0065x; 1.0065x over previous
//
#include <hip/hip_runtime.h>
#include <math.h>

#define B_  16
#define T_  16
#define N_  256
#define D_  384
#define Q_  384
#define K_  16
#define BT_ (B_ * T_)

typedef float f32x4 __attribute__((ext_vector_type(4)));

// R19 = R17 (best, 31.92us) with qproj reading queries DIRECTLY from global
// (96-thread groups share the same 48 scalars -> L1 broadcast). Deletes the
// s_q LDS stage + the kernel's opening __syncthreads; patch prefetch is now
// the first thing issued. R18's redundant-reduce eZSK reverted to R17 form.
__global__ __launch_bounds__(1024, 4)
void fused_kernel(const float* __restrict__ queries,  // [BT_, Q_]
                  const float* __restrict__ patch,    // [BT_, N_, D_]
                  const float* __restrict__ W_in,     // [Q_, D_]
                  const float* __restrict__ b_in,     // [D_]
                  const float* __restrict__ W_out,    // [D_, Q_]
                  const float* __restrict__ b_out,    // [Q_]
                  float* __restrict__ out)            // [BT_, Q_]
{
    const int bt   = blockIdx.x;
    const int tid  = threadIdx.x;       // 0..1023
    const int lane = tid & 63;
    const int wave = tid >> 6;          // 0..15

    __shared__ __align__(16) float s_qp[D_];
    __shared__ __align__(16) float s_sc[N_];
    __shared__ __align__(16) unsigned s_ku[N_];   // rank keys
    __shared__ __align__(16) int   s_cnt4[N_][4];
    __shared__ float s_red[4];
    __shared__ float s_red2[4][2];
    __shared__ float s_w[K_];
    __shared__ int   s_ix[K_];
    __shared__ __align__(16) float s_p8[8][D_];   // split-K partials (reused)
    __shared__ __align__(16) float s_od[D_];

    const float* __restrict__ ptile = patch   + (size_t)bt * N_ * D_;
    const float* __restrict__ qrow  = queries + (size_t)bt * Q_;

    const int g16 = lane >> 4;          // 0..3
    const int sl  = lane & 15;
    const int n0  = wave * 4 + g16;     // rows n0 + {0,64,128,192}

    f32x4 A[6], Bu[6], C[6];

#define LOADROW(dst, it) {                                                     \
        const float* pr = ptile + (size_t)(n0 + (it) * 64) * D_;               \
        _Pragma("unroll")                                                      \
        for (int c = 0; c < 6; ++c)                                            \
            dst[c] = __builtin_nontemporal_load(                               \
                reinterpret_cast<const f32x4*>(pr + c * 64 + 4 * sl)); }

#define DOTSTORE(src, it) {                                                    \
        float p = 0.f;                                                         \
        _Pragma("unroll")                                                      \
        for (int c = 0; c < 6; ++c)                                            \
            p += src[c].x * qv[c].x + src[c].y * qv[c].y                       \
               + src[c].z * qv[c].z + src[c].w * qv[c].w;                      \
        _Pragma("unroll")                                                      \
        for (int off = 8; off; off >>= 1) p += __shfl_xor(p, off, 16);         \
        if (sl == 0) {                                                         \
            const int nn = n0 + (it) * 64;                                     \
            s_sc[nn] = p;                                                      \
            const unsigned u = __float_as_uint(p);                             \
            const unsigned ord = u ^ ((unsigned)((int)u >> 31) | 0x80000000u); \
            s_ku[nn] = (ord & 0xFFFFFF00u) | (255u - (unsigned)nn);            \
        } }

    // ---- patch prefetch rows 0,1,2: the very first instructions issued ----
    LOADROW(A, 0)
    LOADROW(Bu, 1)
    LOADROW(C, 2)
    __builtin_amdgcn_sched_barrier(0);  // pin prefetch issue before qproj

    // ---- q_proj while prefetch streams: 768 thr, 8-way split-K, float4 W;
    //      queries read direct from global (L1 broadcast across 96-thr group)
    if (tid < 768) {
        const int s = tid / 96;         // k-split 0..7 -> q in [s*48, s*48+48)
        const int g = tid % 96;         // output cols 4g..4g+3
        float4 acc = {0.f, 0.f, 0.f, 0.f};
        const float* wp = W_in + (size_t)(s * 48) * D_ + 4 * g;
        const float* qs = qrow + s * 48;
        #pragma unroll 4
        for (int qq = 0; qq < 48; ++qq) {
            const float4 w = *reinterpret_cast<const float4*>(wp + (size_t)qq * D_);
            const float q = qs[qq];
            acc.x += q * w.x; acc.y += q * w.y;
            acc.z += q * w.z; acc.w += q * w.w;
        }
        *reinterpret_cast<float4*>(&s_p8[s][4 * g]) = acc;
    }
    __syncthreads();
    if (tid < D_) {
        float v = b_in[tid];
        #pragma unroll
        for (int s = 0; s < 8; ++s) v += s_p8[s][tid];
        s_qp[tid] = v;
    }
    __syncthreads();   // prefetch has arrived under qproj

    // ---- scores: rows 0,1,2 from prefetch; row 3 pipelined ----
    {
        const f32x4* s_qp4 = reinterpret_cast<const f32x4*>(s_qp);
        f32x4 qv[6];
        #pragma unroll
        for (int c = 0; c < 6; ++c) qv[c] = s_qp4[c * 16 + sl];

        DOTSTORE(A, 0)
        LOADROW(A, 3)
        DOTSTORE(Bu, 1)
        DOTSTORE(C, 2)
        DOTSTORE(A, 3)
    }
#undef LOADROW
#undef DOTSTORE
    __syncthreads();

    // ---- block max (waves 0-3) + key rank counts (all 1024 thr, rotated) ----
    if (tid < N_) {
        float v = s_sc[tid];
        #pragma unroll
        for (int off = 32; off; off >>= 1) v = fmaxf(v, __shfl_xor(v, off));
        if (lane == 0) s_red[wave] = v;
    }
    {
        const int i   = tid >> 2;       // 0..255
        const int sub = tid & 3;        // chunk [sub*64, sub*64+64)
        const unsigned ki = s_ku[i];
        const uint4* k4 = reinterpret_cast<const uint4*>(s_ku);
        int c = 0;
        #pragma unroll
        for (int jj = 0; jj < 16; ++jj) {
            const int jr = (jj + sub * 4) & 15;          // rotate start
            const uint4 v = k4[sub * 16 + jr];
            c += (int)(v.x > ki) + (int)(v.y > ki)
               + (int)(v.z > ki) + (int)(v.w > ki);
        }
        s_cnt4[i][sub] = c;
    }
    __syncthreads();

    // ---- e, Z, SK (threads < 256) ----
    float e = 0.f;
    int   cnt = N_;
    if (tid < N_) {
        const float mx = fmaxf(fmaxf(s_red[0], s_red[1]), fmaxf(s_red[2], s_red[3]));
        const int4 c4 = reinterpret_cast<const int4*>(s_cnt4)[tid];
        cnt = c4.x + c4.y + c4.z + c4.w;
        e = __expf(s_sc[tid] - mx);

        float z  = e;
        float sk = (cnt < K_) ? e : 0.f;
        #pragma unroll
        for (int off = 32; off; off >>= 1) {
            z  += __shfl_xor(z, off);
            sk += __shfl_xor(sk, off);
        }
        if (lane == 0) { s_red2[wave][0] = z; s_red2[wave][1] = sk; }
    }
    __syncthreads();

    // weight_i = softmax_i / (sum_topk + EPS) = e_i / (SK + EPS*Z)
    {
        const float Z  = s_red2[0][0] + s_red2[1][0] + s_red2[2][0] + s_red2[3][0];
        const float SK = s_red2[0][1] + s_red2[1][1] + s_red2[2][1] + s_red2[3][1];
        const float inv = 1.f / (SK + 1e-8f * Z);
        if (tid < N_ && cnt < K_) {
            s_ix[cnt] = tid;
            s_w[cnt]  = e * inv;
        }
    }
    __syncthreads();

    // ---- W_out prefetch (independent of s_od) + weighted sum over K rows ----
    float4 wpre[8];
    const float* wp = W_out;
    if (tid < 768) {
        const int s = tid / 96;
        const int g = tid % 96;
        wp = W_out + (size_t)(s * 48) * Q_ + 4 * g;
        #pragma unroll
        for (int p = 0; p < 8; ++p)
            wpre[p] = *reinterpret_cast<const float4*>(wp + (size_t)p * Q_);
    }
    __builtin_amdgcn_sched_barrier(0);  // issue W_out loads before wsum

    if (tid < D_) {
        float a0 = 0.f, a1 = 0.f, a2 = 0.f, a3 = 0.f;
        #pragma unroll
        for (int j = 0; j < K_; j += 4) {
            a0 += s_w[j + 0] * ptile[(size_t)s_ix[j + 0] * D_ + tid];
            a1 += s_w[j + 1] * ptile[(size_t)s_ix[j + 1] * D_ + tid];
            a2 += s_w[j + 2] * ptile[(size_t)s_ix[j + 2] * D_ + tid];
            a3 += s_w[j + 3] * ptile[(size_t)s_ix[j + 3] * D_ + tid];
        }
        s_od[tid] = (a0 + a1) + (a2 + a3);
    }
    __syncthreads();

    // ---- out-proj: 768 thr, 8-way split-K; 8 prefetched + 40 streamed ----
    if (tid < 768) {
        const int s = tid / 96;
        const int g = tid % 96;
        const int base = s * 48;
        float4 acc = {0.f, 0.f, 0.f, 0.f};
        #pragma unroll
        for (int p = 0; p < 8; ++p) {
            const float ov = s_od[base + p];
            acc.x += ov * wpre[p].x; acc.y += ov * wpre[p].y;
            acc.z += ov * wpre[p].z; acc.w += ov * wpre[p].w;
        }
        #pragma unroll 4
        for (int dd = 8; dd < 48; ++dd) {
            const float4 w = *reinterpret_cast<const float4*>(wp + (size_t)dd * Q_);
            const float ov = s_od[base + dd];
            acc.x += ov * w.x; acc.y += ov * w.y;
            acc.z += ov * w.z; acc.w += ov * w.w;
        }
        *reinterpret_cast<float4*>(&s_p8[s][4 * g]) = acc;
    }
    __syncthreads();
    if (tid < Q_) {
        float v = b_out[tid];
        #pragma unroll
        for (int s = 0; s < 8; ++s) v += s_p8[s][tid];
        out[(size_t)bt * Q_ + tid] = v;
    }
}

extern "C" void kernel_launch(void* const* d_in, const int* in_sizes, int n_in,
                              void* d_out, int out_size, void* d_ws, size_t ws_size,
                              hipStream_t stream) {
    const float* queries = (const float*)d_in[0];
    const float* patch   = (const float*)d_in[1];
    const float* W_in    = (const float*)d_in[2];
    const float* b_in    = (const float*)d_in[3];
    const float* W_out   = (const float*)d_in[4];
    const float* b_out   = (const float*)d_in[5];
    float* out = (float*)d_out;

    fused_kernel<<<dim3(BT_), dim3(1024), 0, stream>>>(
        queries, patch, W_in, b_in, W_out, b_out, out);
}

// Round 20
// 31.922 us; speedup vs baseline: 1.0203x; 1.0137x over previous
//
#include <hip/hip_runtime.h>
#include <math.h>

#define B_  16
#define T_  16
#define N_  256
#define D_  384
#define Q_  384
#define K_  16
#define BT_ (B_ * T_)

typedef float f32x4 __attribute__((ext_vector_type(4)));

// FINAL (R17, best measured 31.92us): fused single kernel, 256 blocks x 1024.
//  - 3-row patch prefetch issued first, streams under the W_in GEMV (qproj).
//  - scores: 16-lane-group dot products, row 3 pipelined, nt loads (evict-
//    first in L2 so weights stay L2-resident).
//  - top-K: u32 key rank-count (2 VALU/elem, conflict-free rotated float4),
//    deterministic permutation ranks, jax tie-break by index.
//  - renorm algebra: w_i = e_i / (SK + EPS*Z)  (no softmax materialization).
//  - wsum: 16 L2-hot rows, 4 chains; W_out 8-deep prefetch hides its latency.
//  - outproj: 8-way split-K float4 GEMV + LDS combine.
// Structure locked: R8/R12/R15/R16 structural variants all regressed.
__global__ __launch_bounds__(1024, 4)
void fused_kernel(const float* __restrict__ queries,  // [BT_, Q_]
                  const float* __restrict__ patch,    // [BT_, N_, D_]
                  const float* __restrict__ W_in,     // [Q_, D_]
                  const float* __restrict__ b_in,     // [D_]
                  const float* __restrict__ W_out,    // [D_, Q_]
                  const float* __restrict__ b_out,    // [Q_]
                  float* __restrict__ out)            // [BT_, Q_]
{
    const int bt   = blockIdx.x;
    const int tid  = threadIdx.x;       // 0..1023
    const int lane = tid & 63;
    const int wave = tid >> 6;          // 0..15

    __shared__ __align__(16) float s_q[Q_];
    __shared__ __align__(16) float s_qp[D_];
    __shared__ __align__(16) float s_sc[N_];
    __shared__ __align__(16) unsigned s_ku[N_];   // rank keys
    __shared__ __align__(16) int   s_cnt4[N_][4];
    __shared__ float s_red[4];
    __shared__ float s_red2[4][2];
    __shared__ float s_w[K_];
    __shared__ int   s_ix[K_];
    __shared__ __align__(16) float s_p8[8][D_];   // split-K partials (reused)
    __shared__ __align__(16) float s_od[D_];

    const float* __restrict__ ptile = patch + (size_t)bt * N_ * D_;

    // ---- stage query row ----
    if (tid < Q_) s_q[tid] = queries[(size_t)bt * Q_ + tid];
    __syncthreads();

    const int g16 = lane >> 4;          // 0..3
    const int sl  = lane & 15;
    const int n0  = wave * 4 + g16;     // rows n0 + {0,64,128,192}

    f32x4 A[6], Bu[6], C[6];

#define LOADROW(dst, it) {                                                     \
        const float* pr = ptile + (size_t)(n0 + (it) * 64) * D_;               \
        _Pragma("unroll")                                                      \
        for (int c = 0; c < 6; ++c)                                            \
            dst[c] = __builtin_nontemporal_load(                               \
                reinterpret_cast<const f32x4*>(pr + c * 64 + 4 * sl)); }

#define DOTSTORE(src, it) {                                                    \
        float p = 0.f;                                                         \
        _Pragma("unroll")                                                      \
        for (int c = 0; c < 6; ++c)                                            \
            p += src[c].x * qv[c].x + src[c].y * qv[c].y                       \
               + src[c].z * qv[c].z + src[c].w * qv[c].w;                      \
        _Pragma("unroll")                                                      \
        for (int off = 8; off; off >>= 1) p += __shfl_xor(p, off, 16);         \
        if (sl == 0) {                                                         \
            const int nn = n0 + (it) * 64;                                     \
            s_sc[nn] = p;                                                      \
            const unsigned u = __float_as_uint(p);                             \
            const unsigned ord = u ^ ((unsigned)((int)u >> 31) | 0x80000000u); \
            s_ku[nn] = (ord & 0xFFFFFF00u) | (255u - (unsigned)nn);            \
        } }

    // ---- issue patch prefetch rows 0,1,2 (independent of q_proj) ----
    LOADROW(A, 0)
    LOADROW(Bu, 1)
    LOADROW(C, 2)
    __builtin_amdgcn_sched_barrier(0);  // pin prefetch issue before qproj

    // ---- q_proj while prefetch streams: 768 thr, 8-way split-K, float4 W ----
    if (tid < 768) {
        const int s = tid / 96;         // k-split 0..7 -> q in [s*48, s*48+48)
        const int g = tid % 96;         // output cols 4g..4g+3
        float4 acc = {0.f, 0.f, 0.f, 0.f};
        const float* wp = W_in + (size_t)(s * 48) * D_ + 4 * g;
        #pragma unroll 4
        for (int qq = 0; qq < 48; ++qq) {
            const float4 w = *reinterpret_cast<const float4*>(wp + (size_t)qq * D_);
            const float qs = s_q[s * 48 + qq];
            acc.x += qs * w.x; acc.y += qs * w.y;
            acc.z += qs * w.z; acc.w += qs * w.w;
        }
        *reinterpret_cast<float4*>(&s_p8[s][4 * g]) = acc;
    }
    __syncthreads();
    if (tid < D_) {
        float v = b_in[tid];
        #pragma unroll
        for (int s = 0; s < 8; ++s) v += s_p8[s][tid];
        s_qp[tid] = v;
    }
    __syncthreads();   // prefetch has arrived under qproj

    // ---- scores: rows 0,1,2 from prefetch; row 3 pipelined ----
    {
        const f32x4* s_qp4 = reinterpret_cast<const f32x4*>(s_qp);
        f32x4 qv[6];
        #pragma unroll
        for (int c = 0; c < 6; ++c) qv[c] = s_qp4[c * 16 + sl];

        DOTSTORE(A, 0)
        LOADROW(A, 3)
        DOTSTORE(Bu, 1)
        DOTSTORE(C, 2)
        DOTSTORE(A, 3)
    }
#undef LOADROW
#undef DOTSTORE
    __syncthreads();

    // ---- block max (waves 0-3) + key rank counts (all 1024 thr, rotated) ----
    if (tid < N_) {
        float v = s_sc[tid];
        #pragma unroll
        for (int off = 32; off; off >>= 1) v = fmaxf(v, __shfl_xor(v, off));
        if (lane == 0) s_red[wave] = v;
    }
    {
        const int i   = tid >> 2;       // 0..255
        const int sub = tid & 3;        // chunk [sub*64, sub*64+64)
        const unsigned ki = s_ku[i];
        const uint4* k4 = reinterpret_cast<const uint4*>(s_ku);
        int c = 0;
        #pragma unroll
        for (int jj = 0; jj < 16; ++jj) {
            const int jr = (jj + sub * 4) & 15;          // rotate start
            const uint4 v = k4[sub * 16 + jr];
            c += (int)(v.x > ki) + (int)(v.y > ki)
               + (int)(v.z > ki) + (int)(v.w > ki);
        }
        s_cnt4[i][sub] = c;
    }
    __syncthreads();

    // ---- e, Z, SK (threads < 256) ----
    float e = 0.f;
    int   cnt = N_;
    if (tid < N_) {
        const float mx = fmaxf(fmaxf(s_red[0], s_red[1]), fmaxf(s_red[2], s_red[3]));
        const int4 c4 = reinterpret_cast<const int4*>(s_cnt4)[tid];
        cnt = c4.x + c4.y + c4.z + c4.w;
        e = __expf(s_sc[tid] - mx);

        float z  = e;
        float sk = (cnt < K_) ? e : 0.f;
        #pragma unroll
        for (int off = 32; off; off >>= 1) {
            z  += __shfl_xor(z, off);
            sk += __shfl_xor(sk, off);
        }
        if (lane == 0) { s_red2[wave][0] = z; s_red2[wave][1] = sk; }
    }
    __syncthreads();

    // weight_i = softmax_i / (sum_topk + EPS) = e_i / (SK + EPS*Z)
    {
        const float Z  = s_red2[0][0] + s_red2[1][0] + s_red2[2][0] + s_red2[3][0];
        const float SK = s_red2[0][1] + s_red2[1][1] + s_red2[2][1] + s_red2[3][1];
        const float inv = 1.f / (SK + 1e-8f * Z);
        if (tid < N_ && cnt < K_) {
            s_ix[cnt] = tid;
            s_w[cnt]  = e * inv;
        }
    }
    __syncthreads();

    // ---- W_out prefetch (independent of s_od) + weighted sum over K rows ----
    float4 wpre[8];
    const float* wp = W_out;
    if (tid < 768) {
        const int s = tid / 96;
        const int g = tid % 96;
        wp = W_out + (size_t)(s * 48) * Q_ + 4 * g;
        #pragma unroll
        for (int p = 0; p < 8; ++p)
            wpre[p] = *reinterpret_cast<const float4*>(wp + (size_t)p * Q_);
    }
    __builtin_amdgcn_sched_barrier(0);  // issue W_out loads before wsum

    if (tid < D_) {
        float a0 = 0.f, a1 = 0.f, a2 = 0.f, a3 = 0.f;
        #pragma unroll
        for (int j = 0; j < K_; j += 4) {
            a0 += s_w[j + 0] * ptile[(size_t)s_ix[j + 0] * D_ + tid];
            a1 += s_w[j + 1] * ptile[(size_t)s_ix[j + 1] * D_ + tid];
            a2 += s_w[j + 2] * ptile[(size_t)s_ix[j + 2] * D_ + tid];
            a3 += s_w[j + 3] * ptile[(size_t)s_ix[j + 3] * D_ + tid];
        }
        s_od[tid] = (a0 + a1) + (a2 + a3);
    }
    __syncthreads();

    // ---- out-proj: 768 thr, 8-way split-K; 8 prefetched + 40 streamed ----
    if (tid < 768) {
        const int s = tid / 96;
        const int g = tid % 96;
        const int base = s * 48;
        float4 acc = {0.f, 0.f, 0.f, 0.f};
        #pragma unroll
        for (int p = 0; p < 8; ++p) {
            const float ov = s_od[base + p];
            acc.x += ov * wpre[p].x; acc.y += ov * wpre[p].y;
            acc.z += ov * wpre[p].z; acc.w += ov * wpre[p].w;
        }
        #pragma unroll 4
        for (int dd = 8; dd < 48; ++dd) {
            const float4 w = *reinterpret_cast<const float4*>(wp + (size_t)dd * Q_);
            const float ov = s_od[base + dd];
            acc.x += ov * w.x; acc.y += ov * w.y;
            acc.z += ov * w.z; acc.w += ov * w.w;
        }
        *reinterpret_cast<float4*>(&s_p8[s][4 * g]) = acc;
    }
    __syncthreads();
    if (tid < Q_) {
        float v = b_out[tid];
        #pragma unroll
        for (int s = 0; s < 8; ++s) v += s_p8[s][tid];
        out[(size_t)bt * Q_ + tid] = v;
    }
}

extern "C" void kernel_launch(void* const* d_in, const int* in_sizes, int n_in,
                              void* d_out, int out_size, void* d_ws, size_t ws_size,
                              hipStream_t stream) {
    const float* queries = (const float*)d_in[0];
    const float* patch   = (const float*)d_in[1];
    const float* W_in    = (const float*)d_in[2];
    const float* b_in    = (const float*)d_in[3];
    const float* W_out   = (const float*)d_in[4];
    const float* b_out   = (const float*)d_in[5];
    float* out = (float*)d_out;

    fused_kernel<<<dim3(BT_), dim3(1024), 0, stream>>>(
        queries, patch, W_in, b_in, W_out, b_out, out);
}